// Round 1
// baseline (869.957 us; speedup 1.0000x reference)
//
#include <hip/hip_runtime.h>
#include <hip/hip_bf16.h>

#define D 128

typedef __bf16 bf16x8 __attribute__((ext_vector_type(8)));
typedef float f32x4 __attribute__((ext_vector_type(4)));

__device__ __forceinline__ float b2f(unsigned short u) {
    unsigned int x = ((unsigned int)u) << 16;
    return __builtin_bit_cast(float, x);
}
__device__ __forceinline__ unsigned short f2b(float f) {
    __hip_bfloat16 h = __float2bfloat16(f);
    return __builtin_bit_cast(unsigned short, h);
}

// ---------------- CSR build ----------------
__global__ void hist_kernel(const int* __restrict__ dst, int* __restrict__ counts, int E) {
    int e = blockIdx.x * blockDim.x + threadIdx.x;
    if (e < E) atomicAdd(&counts[dst[e]], 1);
}

__global__ void block_sums_kernel(const int* __restrict__ counts, int* __restrict__ bsum, int N) {
    __shared__ int s[256];
    int b = blockIdx.x, t = threadIdx.x;
    int i0 = b * 1024 + t * 4;
    int v = 0;
#pragma unroll
    for (int j = 0; j < 4; ++j)
        if (i0 + j < N) v += counts[i0 + j];
    s[t] = v;
    __syncthreads();
    for (int off = 128; off > 0; off >>= 1) {
        if (t < off) s[t] += s[t + off];
        __syncthreads();
    }
    if (t == 0) bsum[b] = s[0];
}

// one block per 1024 counts; every block redundantly scans the (<=128) block sums
__global__ void scan_kernel(const int* __restrict__ counts, const int* __restrict__ bsum,
                            int* __restrict__ row_ptr, int N, int nb, int E) {
    __shared__ int sb[128];
    __shared__ int sth[256];
    int b = blockIdx.x, t = threadIdx.x;
    if (t < nb) sb[t] = bsum[t];
    __syncthreads();
    if (t == 0) {
        int run = 0;
        for (int i = 0; i < nb; ++i) { int v = sb[i]; sb[i] = run; run += v; }
    }
    __syncthreads();
    int base = sb[b];
    int i0 = b * 1024 + t * 4;
    int c[4];
    int ls = 0;
#pragma unroll
    for (int j = 0; j < 4; ++j) {
        c[j] = (i0 + j < N) ? counts[i0 + j] : 0;
        ls += c[j];
    }
    sth[t] = ls;
    __syncthreads();
    for (int off = 1; off < 256; off <<= 1) {
        int v = (t >= off) ? sth[t - off] : 0;
        __syncthreads();
        sth[t] += v;
        __syncthreads();
    }
    int run = sth[t] - ls + base;  // exclusive prefix for this thread's first element
#pragma unroll
    for (int j = 0; j < 4; ++j) {
        if (i0 + j < N) row_ptr[i0 + j] = run;
        run += c[j];
    }
    if (b == 0 && t == 0) row_ptr[N] = E;
}

__global__ void scatter_kernel(const int* __restrict__ src, const int* __restrict__ dst,
                               const int* __restrict__ row_ptr, int* __restrict__ cursor,
                               int* __restrict__ col, int E) {
    int e = blockIdx.x * blockDim.x + threadIdx.x;
    if (e < E) {
        int d = dst[e];
        int slot = row_ptr[d] + atomicAdd(&cursor[d], 1);
        col[slot] = src[e];
    }
}

// ---------------- dtype conversion ----------------
__global__ void f32_to_bf16_kernel(const float4* __restrict__ in, ushort4* __restrict__ out, int n4) {
    int i = blockIdx.x * blockDim.x + threadIdx.x;
    if (i < n4) {
        float4 f = in[i];
        ushort4 o;
        o.x = f2b(f.x); o.y = f2b(f.y); o.z = f2b(f.z); o.w = f2b(f.w);
        out[i] = o;
    }
}

// W[l][k][n] (row-major) -> WT[l][n][k] bf16 (so B-fragments are contiguous in k)
__global__ void wtrans_kernel(const float* __restrict__ W1, const float* __restrict__ W2,
                              unsigned short* __restrict__ WT1, unsigned short* __restrict__ WT2,
                              int total) {
    int i = blockIdx.x * blockDim.x + threadIdx.x;
    if (i < total) {
        int l = i >> 14;          // D*D = 16384
        int rem = i & 16383;
        int k = rem >> 7;
        int n = rem & 127;
        int o = (l << 14) + n * D + k;
        WT1[o] = f2b(W1[i]);
        WT2[o] = f2b(W2[i]);
    }
}

// ---------------- aggregation: rst[v] = h[v] + sum_{(u->v)} h[u] ----------------
__global__ void agg_kernel(const unsigned short* __restrict__ h, const int* __restrict__ row_ptr,
                           const int* __restrict__ col, unsigned short* __restrict__ rst) {
    int v = blockIdx.x;
    int t = threadIdx.x;  // feature dim
    int base = v * D + t;
    float acc = b2f(h[base]);
    int e0 = row_ptr[v], e1 = row_ptr[v + 1];
    for (int e = e0; e < e1; ++e) {
        int u = col[e];
        acc += b2f(h[u * D + t]);
    }
    rst[base] = f2b(acc);
}

// ---------------- GEMM: out[N,128] = A[N,128] @ W[128,128] + bias (opt relu) ----------------
// WT is n-major ([n][k]); per wave: all 32 B-frags hoisted to regs, grid-stride over 16-row tiles.
__global__ __launch_bounds__(256, 2) void gemm128_kernel(
        const unsigned short* __restrict__ A, const unsigned short* __restrict__ WT,
        const float* __restrict__ bias, unsigned short* __restrict__ outB,
        float* __restrict__ outF, int relu, int outf32, int ntiles) {
    int lane = threadIdx.x & 63;
    int l15 = lane & 15;
    int lg = lane >> 4;

    bf16x8 bfrag[8][4];
#pragma unroll
    for (int nt = 0; nt < 8; ++nt)
#pragma unroll
        for (int kb = 0; kb < 4; ++kb)
            bfrag[nt][kb] = *(const bf16x8*)(WT + (nt * 16 + l15) * D + kb * 32 + lg * 8);

    float bv[8];
#pragma unroll
    for (int nt = 0; nt < 8; ++nt) bv[nt] = bias[nt * 16 + l15];

    int gw = blockIdx.x * 4 + (threadIdx.x >> 6);
    int nw = gridDim.x * 4;
    for (int tile = gw; tile < ntiles; tile += nw) {
        int m0 = tile << 4;
        const unsigned short* arow = A + (m0 + l15) * D + lg * 8;
        bf16x8 afrag[4];
#pragma unroll
        for (int kb = 0; kb < 4; ++kb) afrag[kb] = *(const bf16x8*)(arow + kb * 32);
        f32x4 acc[8];
#pragma unroll
        for (int nt = 0; nt < 8; ++nt) acc[nt] = (f32x4){0.f, 0.f, 0.f, 0.f};
#pragma unroll
        for (int kb = 0; kb < 4; ++kb)
#pragma unroll
            for (int nt = 0; nt < 8; ++nt)
                acc[nt] = __builtin_amdgcn_mfma_f32_16x16x32_bf16(afrag[kb], bfrag[nt][kb],
                                                                  acc[nt], 0, 0, 0);
        int r0 = m0 + lg * 4;
#pragma unroll
        for (int nt = 0; nt < 8; ++nt) {
            int c = nt * 16 + l15;
#pragma unroll
            for (int r = 0; r < 4; ++r) {
                float val = acc[nt][r] + bv[nt];
                if (relu) val = fmaxf(val, 0.f);
                if (outf32) outF[(r0 + r) * D + c] = val;
                else outB[(r0 + r) * D + c] = f2b(val);
            }
        }
    }
}

extern "C" void kernel_launch(void* const* d_in, const int* in_sizes, int n_in,
                              void* d_out, int out_size, void* d_ws, size_t ws_size,
                              hipStream_t stream) {
    const float* feat = (const float*)d_in[0];
    const float* W1 = (const float*)d_in[1];
    const float* b1 = (const float*)d_in[2];
    const float* W2 = (const float*)d_in[3];
    const float* b2 = (const float*)d_in[4];
    const int* src = (const int*)d_in[5];
    const int* dst = (const int*)d_in[6];

    const int N = in_sizes[0] / D;     // 100000
    const int L = in_sizes[2] / D;     // 3
    const int E = in_sizes[5];         // 1600000

    char* w = (char*)d_ws;
    size_t off = 0;
    auto alloc = [&](size_t bytes) {
        void* p = w + off;
        off = (off + bytes + 255) & ~(size_t)255;
        return p;
    };
    unsigned short* bufH = (unsigned short*)alloc((size_t)N * D * 2);   // h (bf16)
    unsigned short* bufR = (unsigned short*)alloc((size_t)N * D * 2);   // rst / h1 (bf16)
    int* col = (int*)alloc((size_t)E * 4);
    int* row_ptr = (int*)alloc((size_t)(N + 1) * 4);
    int* counts = (int*)alloc((size_t)N * 4);
    (void)alloc(512);  // spare
    unsigned short* WT1 = (unsigned short*)alloc((size_t)L * D * D * 2);
    unsigned short* WT2 = (unsigned short*)alloc((size_t)L * D * D * 2);
    int* bsum = (int*)alloc(512);

    int nb = (N + 1023) / 1024;

    // CSR build (per call: src/dst restored from pristine each timed iteration)
    hipMemsetAsync(counts, 0, (size_t)N * 4, stream);
    hist_kernel<<<(E + 255) / 256, 256, 0, stream>>>(dst, counts, E);
    block_sums_kernel<<<nb, 256, 0, stream>>>(counts, bsum, N);
    scan_kernel<<<nb, 256, 0, stream>>>(counts, bsum, row_ptr, N, nb, E);
    hipMemsetAsync(counts, 0, (size_t)N * 4, stream);
    scatter_kernel<<<(E + 255) / 256, 256, 0, stream>>>(src, dst, row_ptr, counts, col, E);

    // dtype prep
    int n4 = N * D / 4;
    f32_to_bf16_kernel<<<(n4 + 255) / 256, 256, 0, stream>>>((const float4*)feat, (ushort4*)bufH, n4);
    int wtotal = L * D * D;
    wtrans_kernel<<<(wtotal + 255) / 256, 256, 0, stream>>>(W1, W2, WT1, WT2, wtotal);

    int ntiles = N / 16;
    for (int i = 0; i < L; ++i) {
        agg_kernel<<<N, D, 0, stream>>>(bufH, row_ptr, col, bufR);
        int relu = (i < L - 1) ? 1 : 0;
        // GEMM1: rst -> h1 (in place, safe: each wave reads its 16 rows fully before storing them)
        gemm128_kernel<<<512, 256, 0, stream>>>(bufR, WT1 + i * D * D, b1 + i * D,
                                                bufR, nullptr, relu, 0, ntiles);
        int outf32 = (i == L - 1) ? 1 : 0;
        // GEMM2: h1 -> h (bf16) or final output (fp32)
        gemm128_kernel<<<512, 256, 0, stream>>>(bufR, WT2 + i * D * D, b2 + i * D,
                                                bufH, (float*)d_out, relu, outf32, ntiles);
    }
}

// Round 2
// 566.839 us; speedup vs baseline: 1.5348x; 1.5348x over previous
//
#include <hip/hip_runtime.h>
#include <hip/hip_bf16.h>

#define D 128

typedef __bf16 bf16x8 __attribute__((ext_vector_type(8)));
typedef float f32x4 __attribute__((ext_vector_type(4)));
typedef unsigned int u32x4 __attribute__((ext_vector_type(4)));
typedef unsigned short u16x8 __attribute__((ext_vector_type(8)));

__device__ __forceinline__ float b2f(unsigned short u) {
    unsigned int x = ((unsigned int)u) << 16;
    return __builtin_bit_cast(float, x);
}
__device__ __forceinline__ unsigned short f2b(float f) {
    __hip_bfloat16 h = __float2bfloat16(f);
    return __builtin_bit_cast(unsigned short, h);
}

// unpack 4 dwords (8 bf16) and accumulate into 8 fp32
__device__ __forceinline__ void acc8(float* acc, u32x4 x) {
#pragma unroll
    for (int r = 0; r < 4; ++r) {
        acc[2 * r]     += __builtin_bit_cast(float, x[r] << 16);
        acc[2 * r + 1] += __builtin_bit_cast(float, x[r] & 0xffff0000u);
    }
}

// ---------------- CSR build ----------------
__global__ void hist_kernel(const int* __restrict__ dst, int* __restrict__ counts, int E) {
    int e = blockIdx.x * blockDim.x + threadIdx.x;
    if (e < E) atomicAdd(&counts[dst[e]], 1);
}

__global__ void block_sums_kernel(const int* __restrict__ counts, int* __restrict__ bsum, int N) {
    __shared__ int s[256];
    int b = blockIdx.x, t = threadIdx.x;
    int i0 = b * 1024 + t * 4;
    int v = 0;
#pragma unroll
    for (int j = 0; j < 4; ++j)
        if (i0 + j < N) v += counts[i0 + j];
    s[t] = v;
    __syncthreads();
    for (int off = 128; off > 0; off >>= 1) {
        if (t < off) s[t] += s[t + off];
        __syncthreads();
    }
    if (t == 0) bsum[b] = s[0];
}

__global__ void scan_kernel(const int* __restrict__ counts, const int* __restrict__ bsum,
                            int* __restrict__ row_ptr, int N, int nb, int E) {
    __shared__ int sb[128];
    __shared__ int sth[256];
    int b = blockIdx.x, t = threadIdx.x;
    if (t < nb) sb[t] = bsum[t];
    __syncthreads();
    if (t == 0) {
        int run = 0;
        for (int i = 0; i < nb; ++i) { int v = sb[i]; sb[i] = run; run += v; }
    }
    __syncthreads();
    int base = sb[b];
    int i0 = b * 1024 + t * 4;
    int c[4];
    int ls = 0;
#pragma unroll
    for (int j = 0; j < 4; ++j) {
        c[j] = (i0 + j < N) ? counts[i0 + j] : 0;
        ls += c[j];
    }
    sth[t] = ls;
    __syncthreads();
    for (int off = 1; off < 256; off <<= 1) {
        int v = (t >= off) ? sth[t - off] : 0;
        __syncthreads();
        sth[t] += v;
        __syncthreads();
    }
    int run = sth[t] - ls + base;
#pragma unroll
    for (int j = 0; j < 4; ++j) {
        if (i0 + j < N) row_ptr[i0 + j] = run;
        run += c[j];
    }
    if (b == 0 && t == 0) row_ptr[N] = E;
}

__global__ void scatter_kernel(const int* __restrict__ src, const int* __restrict__ dst,
                               const int* __restrict__ row_ptr, int* __restrict__ cursor,
                               int* __restrict__ col, int E) {
    int e = blockIdx.x * blockDim.x + threadIdx.x;
    if (e < E) {
        int d = dst[e];
        int slot = row_ptr[d] + atomicAdd(&cursor[d], 1);
        col[slot] = src[e];
    }
}

// ---------------- dtype conversion ----------------
__global__ void f32_to_bf16_kernel(const float4* __restrict__ in, ushort4* __restrict__ out, int n4) {
    int i = blockIdx.x * blockDim.x + threadIdx.x;
    if (i < n4) {
        float4 f = in[i];
        ushort4 o;
        o.x = f2b(f.x); o.y = f2b(f.y); o.z = f2b(f.z); o.w = f2b(f.w);
        out[i] = o;
    }
}

__global__ void wtrans_kernel(const float* __restrict__ W1, const float* __restrict__ W2,
                              unsigned short* __restrict__ WT1, unsigned short* __restrict__ WT2,
                              int total) {
    int i = blockIdx.x * blockDim.x + threadIdx.x;
    if (i < total) {
        int l = i >> 14;
        int rem = i & 16383;
        int k = rem >> 7;
        int n = rem & 127;
        int o = (l << 14) + n * D + k;
        WT1[o] = f2b(W1[i]);
        WT2[o] = f2b(W2[i]);
    }
}

// ---------------- aggregation: rst[v] = h[v] + sum_{(u->v)} h[u] ----------------
// one wave per node; lane = j*16+i: i = feature block (8 bf16, 16B), j = edge slot.
// 8 edges in flight per iteration (4 slots x unroll 2, two independent acc chains).
__global__ __launch_bounds__(256) void agg_kernel(
        const unsigned short* __restrict__ h, const int* __restrict__ row_ptr,
        const int* __restrict__ col, unsigned short* __restrict__ rst, int N) {
    int lane = threadIdx.x & 63;
    int i = lane & 15;
    int j = lane >> 4;
    int v = blockIdx.x * 4 + (threadIdx.x >> 6);
    if (v >= N) return;

    int e0 = row_ptr[v], e1 = row_ptr[v + 1];

    float accA[8], accB[8];
#pragma unroll
    for (int r = 0; r < 8; ++r) { accA[r] = 0.f; accB[r] = 0.f; }

    // self term: slot 0 lanes accumulate h[v]
    if (j == 0) {
        u32x4 x = *(const u32x4*)(h + (size_t)v * D + i * 8);
        acc8(accA, x);
    }

    int e = e0 + j;
    for (; e + 4 < e1; e += 8) {
        int u0 = col[e];
        int u1 = col[e + 4];
        u32x4 x0 = *(const u32x4*)(h + (size_t)u0 * D + i * 8);
        u32x4 x1 = *(const u32x4*)(h + (size_t)u1 * D + i * 8);
        acc8(accA, x0);
        acc8(accB, x1);
    }
    if (e < e1) {
        int u0 = col[e];
        u32x4 x0 = *(const u32x4*)(h + (size_t)u0 * D + i * 8);
        acc8(accA, x0);
    }

    // reduce the 4 edge slots (lanes differing in bits 4,5)
    unsigned short outv[8];
#pragma unroll
    for (int r = 0; r < 8; ++r) {
        float s = accA[r] + accB[r];
        s += __shfl_xor(s, 16);
        s += __shfl_xor(s, 32);
        outv[r] = f2b(s);
    }
    if (j == 0) {
        u16x8 o;
#pragma unroll
        for (int r = 0; r < 8; ++r) o[r] = outv[r];
        *(u16x8*)(rst + (size_t)v * D + i * 8) = o;
    }
}

// ---------------- GEMM: out[N,128] = A[N,128] @ W[128,128] + bias (opt relu) ----------------
__global__ __launch_bounds__(256, 2) void gemm128_kernel(
        const unsigned short* __restrict__ A, const unsigned short* __restrict__ WT,
        const float* __restrict__ bias, unsigned short* __restrict__ outB,
        float* __restrict__ outF, int relu, int outf32, int ntiles) {
    int lane = threadIdx.x & 63;
    int l15 = lane & 15;
    int lg = lane >> 4;

    bf16x8 bfrag[8][4];
#pragma unroll
    for (int nt = 0; nt < 8; ++nt)
#pragma unroll
        for (int kb = 0; kb < 4; ++kb)
            bfrag[nt][kb] = *(const bf16x8*)(WT + (nt * 16 + l15) * D + kb * 32 + lg * 8);

    float bv[8];
#pragma unroll
    for (int nt = 0; nt < 8; ++nt) bv[nt] = bias[nt * 16 + l15];

    int gw = blockIdx.x * 4 + (threadIdx.x >> 6);
    int nw = gridDim.x * 4;
    for (int tile = gw; tile < ntiles; tile += nw) {
        int m0 = tile << 4;
        const unsigned short* arow = A + (m0 + l15) * D + lg * 8;
        bf16x8 afrag[4];
#pragma unroll
        for (int kb = 0; kb < 4; ++kb) afrag[kb] = *(const bf16x8*)(arow + kb * 32);
        f32x4 acc[8];
#pragma unroll
        for (int nt = 0; nt < 8; ++nt) acc[nt] = (f32x4){0.f, 0.f, 0.f, 0.f};
#pragma unroll
        for (int kb = 0; kb < 4; ++kb)
#pragma unroll
            for (int nt = 0; nt < 8; ++nt)
                acc[nt] = __builtin_amdgcn_mfma_f32_16x16x32_bf16(afrag[kb], bfrag[nt][kb],
                                                                  acc[nt], 0, 0, 0);
        int r0 = m0 + lg * 4;
#pragma unroll
        for (int nt = 0; nt < 8; ++nt) {
            int c = nt * 16 + l15;
#pragma unroll
            for (int r = 0; r < 4; ++r) {
                float val = acc[nt][r] + bv[nt];
                if (relu) val = fmaxf(val, 0.f);
                if (outf32) outF[(r0 + r) * D + c] = val;
                else outB[(r0 + r) * D + c] = f2b(val);
            }
        }
    }
}

extern "C" void kernel_launch(void* const* d_in, const int* in_sizes, int n_in,
                              void* d_out, int out_size, void* d_ws, size_t ws_size,
                              hipStream_t stream) {
    const float* feat = (const float*)d_in[0];
    const float* W1 = (const float*)d_in[1];
    const float* b1 = (const float*)d_in[2];
    const float* W2 = (const float*)d_in[3];
    const float* b2 = (const float*)d_in[4];
    const int* src = (const int*)d_in[5];
    const int* dst = (const int*)d_in[6];

    const int N = in_sizes[0] / D;
    const int L = in_sizes[2] / D;
    const int E = in_sizes[5];

    char* w = (char*)d_ws;
    size_t off = 0;
    auto alloc = [&](size_t bytes) {
        void* p = w + off;
        off = (off + bytes + 255) & ~(size_t)255;
        return p;
    };
    unsigned short* bufH = (unsigned short*)alloc((size_t)N * D * 2);
    unsigned short* bufR = (unsigned short*)alloc((size_t)N * D * 2);
    int* col = (int*)alloc((size_t)E * 4);
    int* row_ptr = (int*)alloc((size_t)(N + 1) * 4);
    int* counts = (int*)alloc((size_t)N * 4);
    (void)alloc(512);
    unsigned short* WT1 = (unsigned short*)alloc((size_t)L * D * D * 2);
    unsigned short* WT2 = (unsigned short*)alloc((size_t)L * D * D * 2);
    int* bsum = (int*)alloc(512);

    int nb = (N + 1023) / 1024;

    hipMemsetAsync(counts, 0, (size_t)N * 4, stream);
    hist_kernel<<<(E + 255) / 256, 256, 0, stream>>>(dst, counts, E);
    block_sums_kernel<<<nb, 256, 0, stream>>>(counts, bsum, N);
    scan_kernel<<<nb, 256, 0, stream>>>(counts, bsum, row_ptr, N, nb, E);
    hipMemsetAsync(counts, 0, (size_t)N * 4, stream);
    scatter_kernel<<<(E + 255) / 256, 256, 0, stream>>>(src, dst, row_ptr, counts, col, E);

    int n4 = N * D / 4;
    f32_to_bf16_kernel<<<(n4 + 255) / 256, 256, 0, stream>>>((const float4*)feat, (ushort4*)bufH, n4);
    int wtotal = L * D * D;
    wtrans_kernel<<<(wtotal + 255) / 256, 256, 0, stream>>>(W1, W2, WT1, WT2, wtotal);

    int ntiles = N / 16;
    int aggBlocks = (N + 3) / 4;
    for (int i = 0; i < L; ++i) {
        agg_kernel<<<aggBlocks, 256, 0, stream>>>(bufH, row_ptr, col, bufR, N);
        int relu = (i < L - 1) ? 1 : 0;
        gemm128_kernel<<<512, 256, 0, stream>>>(bufR, WT1 + i * D * D, b1 + i * D,
                                                bufR, nullptr, relu, 0, ntiles);
        int outf32 = (i == L - 1) ? 1 : 0;
        gemm128_kernel<<<512, 256, 0, stream>>>(bufR, WT2 + i * D * D, b2 + i * D,
                                                bufH, (float*)d_out, relu, outf32, ntiles);
    }
}